// Round 5
// baseline (240.107 us; speedup 1.0000x reference)
//
#include <hip/hip_runtime.h>
#include <hip/hip_bf16.h>

#define L 256
#define DH 512
#define NBLK 256
#define NTHR 512
#define MAT 262144    // 512*512

typedef __attribute__((ext_vector_type(8))) short bf16x8;
typedef __attribute__((ext_vector_type(4))) float f32x4;

static __device__ __forceinline__ ushort f2b(float v) {
  __hip_bfloat16 h = __float2bfloat16(v);
  return *(ushort*)&h;
}

struct PARAMS {
  const float *x, *fcw, *fcb, *b1, *b2, *bl, *bf;
  const float *w1, *w2, *wf1, *wf2;
  float *out, *rep, *g1, *attn, *hsc, *dr;
  ushort *xb, *repb, *attnb, *fcwt, *w1t, *w2t, *wf1t, *wf2t;
  int *bar;          // [0]=count, [1]=generation (memset to 0 each call)
};

// sense-forward grid barrier: 1 arrival per block, AGENT-scope acq/rel.
__device__ __forceinline__ void gridbar(int* bar, int phase) {
  __syncthreads();
  if (threadIdx.x == 0) {
    __threadfence();   // release prior writes to device scope
    const int prev = __hip_atomic_fetch_add(&bar[0], 1, __ATOMIC_ACQ_REL,
                                            __HIP_MEMORY_SCOPE_AGENT);
    if (prev == NBLK - 1) {
      __hip_atomic_store(&bar[0], 0, __ATOMIC_RELAXED, __HIP_MEMORY_SCOPE_AGENT);
      __hip_atomic_store(&bar[1], phase, __ATOMIC_RELEASE, __HIP_MEMORY_SCOPE_AGENT);
    } else {
      while (__hip_atomic_load(&bar[1], __ATOMIC_ACQUIRE,
                               __HIP_MEMORY_SCOPE_AGENT) < phase)
        __builtin_amdgcn_s_sleep(1);
    }
  }
  __syncthreads();
}

// 16x16 output tile, K=512, one wave. A,Bt both [row][K] bf16 K-major.
__device__ __forceinline__ void gemm16(const ushort* __restrict__ A,
                                       const ushort* __restrict__ Bt,
                                       int m0, int n0, f32x4& acc)
{
  const int l  = threadIdx.x & 63;
  const int fr = l & 15, kg = (l >> 4) << 3;
  const ushort* pa = A  + (size_t)(m0 + fr) * DH + kg;
  const ushort* pb = Bt + (size_t)(n0 + fr) * DH + kg;
#pragma unroll 8
  for (int kt = 0; kt < DH; kt += 32) {
    const bf16x8 a = *(const bf16x8*)(pa + kt);
    const bf16x8 b = *(const bf16x8*)(pb + kt);
    acc = __builtin_amdgcn_mfma_f32_16x16x32_bf16(a, b, acc, 0, 0, 0);
  }
}

__global__ __launch_bounds__(NTHR) void mega(PARAMS p)
{
  const int tid  = threadIdx.x;
  const int bid  = blockIdx.x;
  const int widx = tid >> 6;
  const int lane = tid & 63;
  const float c1  = 0.57707801635558534f;   // 2*log2(e)/C
  const float Ac  = 7.2134752044448169f;    // C*log2(e)
  const float Bc  = 14.426950408889634f;    // 2C*log2(e)
  const float l2e = 1.4426950408889634f;

  // ---------- P0: cast x -> xb ; transpose+cast 5 weights to [N][K] bf16 ----------
  {
    const int gid = bid * NTHR + tid;
    if (gid < 65536) {
      const float4 v = ((const float4*)p.x)[gid];
      ushort4 o; o.x = f2b(v.x); o.y = f2b(v.y); o.z = f2b(v.z); o.w = f2b(v.w);
      ((ushort4*)p.xb)[gid] = o;
    }
    __shared__ float tr[32][33];
    const int tx = tid & 31, ty = tid >> 5;             // ty in [0,16)
    const int r0 = (bid >> 4) << 5, c0 = (bid & 15) << 5;
    const float* srcs[5] = {p.fcw, p.w1, p.w2, p.wf1, p.wf2};
    ushort*      dsts[5] = {p.fcwt, p.w1t, p.w2t, p.wf1t, p.wf2t};
#pragma unroll
    for (int s = 0; s < 5; ++s) {
      __syncthreads();
      tr[ty][tx]      = srcs[s][(size_t)(r0 + ty) * DH + c0 + tx];
      tr[ty + 16][tx] = srcs[s][(size_t)(r0 + ty + 16) * DH + c0 + tx];
      __syncthreads();
      dsts[s][(size_t)(c0 + ty) * DH + r0 + tx]      = f2b(tr[tx][ty]);
      dsts[s][(size_t)(c0 + ty + 16) * DH + r0 + tx] = f2b(tr[tx][ty + 16]);
    }
  }
  gridbar(p.bar, 1);

  // ---------- P1: rep = elu(x@fc_w + fc_b); writes rep f32, repb bf16, dr.y ----------
  {
    const int wv = widx * NBLK + bid;
    if (wv < 1024) {
      const int m0 = (wv >> 5) << 4, n0 = (wv & 31) << 4;
      f32x4 acc = {};
      gemm16(p.xb, p.fcwt, m0, n0, acc);
      const int fr = lane & 15, rg = (lane >> 4) << 2;
      const int col = n0 + fr;
      const float bv = p.fcb[col];
#pragma unroll
      for (int r = 0; r < 4; ++r) {
        float v = acc[r] + bv;
        v = v > 0.0f ? v : (__builtin_amdgcn_exp2f(v * l2e) - 1.0f);
        const size_t idx = (size_t)(m0 + rg + r) * DH + col;
        p.rep[idx]  = v;
        p.repb[idx] = f2b(v);
        p.dr[idx * 2 + 1] = v;
      }
    }
  }
  gridbar(p.bar, 2);

  // ---------- P2: dr.x=(rep@w1+b1+bl)*c1 ; hsc=(rep@w2+b2)*c1 ; g1=rep@wf1 ----------
  {
    const int wv = widx * NBLK + bid;
    for (int tt = wv; tt < 3072; tt += 2048) {
      const int z = tt >> 10, rem = tt & 1023;
      const int m0 = (rem >> 5) << 4, n0 = (rem & 31) << 4;
      const ushort* Bt = (z == 0) ? p.w1t : (z == 1) ? p.w2t : p.wf1t;
      f32x4 acc = {};
      gemm16(p.repb, Bt, m0, n0, acc);
      const int fr = lane & 15, rg = (lane >> 4) << 2;
      const int col = n0 + fr;
#pragma unroll
      for (int r = 0; r < 4; ++r) {
        const size_t idx = (size_t)(m0 + rg + r) * DH + col;
        if (z == 0)      p.dr[idx * 2] = (acc[r] + p.b1[col] + p.bl[col]) * c1;
        else if (z == 1) p.hsc[idx]    = (acc[r] + p.b2[col]) * c1;
        else             p.g1[idx]     = acc[r];
      }
    }
  }
  gridbar(p.bar, 3);

  // ---------- P3: masked tanh-clip softmax attention, rows {i, 255-i} per block ----------
  // w = exp(C*tanh(s/C)) = 2^(Ac - Bc/(2^(d'+hb)+1)); row 255 fully masked -> uniform.
  {
    const int b = bid >> 7, i1 = bid & 127, i2 = 255 - i1;
    const int h = tid;
    const bool special = (i1 == 0);                    // pair contains row 255
    const float hb1 = p.hsc[((size_t)b * L + i1) * DH + h];
    const float hb2 = p.hsc[((size_t)b * L + i2) * DH + h];
    const float2* drp = (const float2*)p.dr + (size_t)b * L * DH + h;
    float sa1 = 0.0f, aa1 = 0.0f, sa2 = 0.0f, aa2 = 0.0f;
    const int jstart = special ? 0 : (i1 + 1);
    for (int j = jstart; j < L; ++j) {
      const float2 v = drp[(size_t)j * DH];            // {d*c1, rep}
      if (j > i1) {                                    // block-uniform
        const float E = __builtin_amdgcn_exp2f(v.x + hb1);
        const float w = __builtin_amdgcn_exp2f(
            fmaf(-Bc, __builtin_amdgcn_rcpf(E + 1.0f), Ac));
        sa1 += w; aa1 = fmaf(w, v.y, aa1);
      }
      if (special) {                                   // row 255: uniform weights
        sa2 += 1.0f; aa2 += v.y;
      } else if (j > i2) {
        const float E = __builtin_amdgcn_exp2f(v.x + hb2);
        const float w = __builtin_amdgcn_exp2f(
            fmaf(-Bc, __builtin_amdgcn_rcpf(E + 1.0f), Ac));
        sa2 += w; aa2 = fmaf(w, v.y, aa2);
      }
    }
    const float v1 = aa1 * __builtin_amdgcn_rcpf(sa1);
    const float v2 = aa2 * __builtin_amdgcn_rcpf(sa2);
    const size_t o1 = ((size_t)b * L + i1) * DH + h;
    const size_t o2 = ((size_t)b * L + i2) * DH + h;
    p.attn[o1] = v1; p.attnb[o1] = f2b(v1);
    p.attn[o2] = v2; p.attnb[o2] = f2b(v2);
  }
  gridbar(p.bar, 4);

  // ---------- P4: g2 = attn@wf2 ; gate = sigmoid(g1+g2+bf) ; out = mix ----------
  {
    const int wv = widx * NBLK + bid;
    if (wv < 1024) {
      const int m0 = (wv >> 5) << 4, n0 = (wv & 31) << 4;
      f32x4 acc = {};
      gemm16(p.attnb, p.wf2t, m0, n0, acc);
      const int fr = lane & 15, rg = (lane >> 4) << 2;
      const int col = n0 + fr;
      const float bv = p.bf[col];
#pragma unroll
      for (int r = 0; r < 4; ++r) {
        const size_t idx = (size_t)(m0 + rg + r) * DH + col;
        const float s = p.g1[idx] + acc[r] + bv;
        const float gate = __builtin_amdgcn_rcpf(
            1.0f + __builtin_amdgcn_exp2f(-s * l2e));
        p.out[idx] = gate * p.rep[idx] + (1.0f - gate) * p.attn[idx];
      }
    }
  }
}

extern "C" void kernel_launch(void* const* d_in, const int* in_sizes, int n_in,
                              void* d_out, int out_size, void* d_ws, size_t ws_size,
                              hipStream_t stream)
{
  PARAMS p;
  p.x   = (const float*)d_in[0];
  p.fcw = (const float*)d_in[1];
  p.fcb = (const float*)d_in[2];
  p.w1  = (const float*)d_in[3];
  p.b1  = (const float*)d_in[4];
  p.w2  = (const float*)d_in[5];
  p.b2  = (const float*)d_in[6];
  p.bl  = (const float*)d_in[7];
  p.wf1 = (const float*)d_in[8];
  p.wf2 = (const float*)d_in[9];
  p.bf  = (const float*)d_in[10];
  p.out = (float*)d_out;

  float* ws = (float*)d_ws;
  p.rep  = ws;                 // MAT
  p.g1   = ws + 1 * MAT;       // MAT
  p.attn = ws + 2 * MAT;       // MAT
  p.hsc  = ws + 3 * MAT;       // MAT
  p.dr   = ws + 4 * MAT;       // 2*MAT (float2 {d*c1, rep})
  ushort* ub = (ushort*)(ws + 6 * MAT);
  p.xb    = ub + 0 * MAT;
  p.repb  = ub + 1 * MAT;
  p.attnb = ub + 2 * MAT;
  p.fcwt  = ub + 3 * MAT;
  p.w1t   = ub + 4 * MAT;
  p.w2t   = ub + 5 * MAT;
  p.wf1t  = ub + 6 * MAT;
  p.wf2t  = ub + 7 * MAT;
  p.bar   = (int*)(ws + 12 * MAT);   // isolated cacheline region

  hipMemsetAsync(p.bar, 0, 2 * sizeof(int), stream);
  void* args[] = { &p };
  hipLaunchCooperativeKernel((void*)mega, dim3(NBLK), dim3(NTHR), args, 0, stream);
}

// Round 6
// 119.511 us; speedup vs baseline: 2.0091x; 2.0091x over previous
//
#include <hip/hip_runtime.h>
#include <hip/hip_bf16.h>

#define L 256
#define DH 512
#define NBLK 256
#define NTHR 512
#define MAT 262144
#define AGT __HIP_MEMORY_SCOPE_AGENT

typedef __attribute__((ext_vector_type(8))) short bf16x8;
typedef __attribute__((ext_vector_type(4))) float f32x4;
typedef unsigned long long u64;

static __device__ __forceinline__ ushort f2b(float v) {
  __hip_bfloat16 h = __float2bfloat16(v);
  return *(ushort*)&h;
}
// ---- coherent (Infinity-Cache-resident) access: agent-scope relaxed atomics.
// These bypass the non-cross-coherent per-XCD L1/L2, so grid barriers need
// NO cache maintenance (no buffer_wbl2 / buffer_inv storms).
static __device__ __forceinline__ float cldf(const float* p) {
  return __hip_atomic_load(p, __ATOMIC_RELAXED, AGT);
}
static __device__ __forceinline__ u64 cld8(const void* p) {
  return __hip_atomic_load((const u64*)p, __ATOMIC_RELAXED, AGT);
}
static __device__ __forceinline__ void cstf(float* p, float v) {
  __hip_atomic_store(p, v, __ATOMIC_RELAXED, AGT);
}
static __device__ __forceinline__ void csth(ushort* p, ushort v) {
  __hip_atomic_store(p, v, __ATOMIC_RELAXED, AGT);
}
static __device__ __forceinline__ bf16x8 ldfrag_c(const ushort* p) {
  union { bf16x8 v; u64 q[2]; } u;
  u.q[0] = cld8(p); u.q[1] = cld8(p + 4);
  return u.v;
}

struct PARAMS {
  const float *fcb, *b1, *b2, *bl, *bf;
  float *out, *rep, *g1, *attn, *hsc, *dr;
  const ushort *xb, *fcwt, *w1t, *w2t, *wf1t, *wf2t;
  ushort *repb, *attnb;
  int *bar;   // 3 phases x 512 ints, zeroed each call
};

// relaxed-only hierarchical grid barrier: 8 group lines x 32 arrivals -> root(8) -> release
static __device__ __forceinline__ void gridbar(int* bar, int ph) {
  __syncthreads();                               // drains vmcnt(0): sc1 stores visible at IF
  if (threadIdx.x == 0) {
    int* base = bar + ph * 512;
    int* cnt  = base + (blockIdx.x & 7) * 32;
    if (__hip_atomic_fetch_add(cnt, 1, __ATOMIC_RELAXED, AGT) == 31) {
      if (__hip_atomic_fetch_add(base + 256, 1, __ATOMIC_RELAXED, AGT) == 7)
        __hip_atomic_store(base + 288, 1, __ATOMIC_RELAXED, AGT);
    }
    while (!__hip_atomic_load(base + 288, __ATOMIC_RELAXED, AGT))
      __builtin_amdgcn_s_sleep(2);
  }
  __syncthreads();
}

// ---------- conv dispatch: cast x -> xb ; transpose+cast 5 weights to [N][K] bf16 ----------
__global__ __launch_bounds__(256) void k_conv(
    const float* __restrict__ x,
    const float* __restrict__ fcw, const float* __restrict__ w1,
    const float* __restrict__ w2, const float* __restrict__ wf1,
    const float* __restrict__ wf2,
    ushort* __restrict__ xb,
    ushort* __restrict__ fcwt, ushort* __restrict__ w1t,
    ushort* __restrict__ w2t, ushort* __restrict__ wf1t,
    ushort* __restrict__ wf2t)
{
  const int z = blockIdx.z;
  const float* src; ushort* dst;
  switch (z) {
    case 0: src = fcw; dst = fcwt; break;
    case 1: src = w1;  dst = w1t;  break;
    case 2: src = w2;  dst = w2t;  break;
    case 3: src = wf1; dst = wf1t; break;
    case 4: src = wf2; dst = wf2t; break;
    default: src = x;  dst = xb;   break;
  }
  const int tx = threadIdx.x & 31, ty = threadIdx.x >> 5;
  const int c0 = blockIdx.x * 32, r0 = blockIdx.y * 32;
  if (z == 5) {
#pragma unroll
    for (int r = 0; r < 4; ++r) {
      const int row = r0 + ty + 8 * r;
      dst[(size_t)row * DH + c0 + tx] = f2b(src[(size_t)row * DH + c0 + tx]);
    }
  } else {
    __shared__ float t[32][33];
#pragma unroll
    for (int r = 0; r < 4; ++r)
      t[ty + 8 * r][tx] = src[(size_t)(r0 + ty + 8 * r) * DH + c0 + tx];
    __syncthreads();
#pragma unroll
    for (int r = 0; r < 4; ++r)
      dst[(size_t)(c0 + ty + 8 * r) * DH + r0 + tx] = f2b(t[tx][ty + 8 * r]);
  }
}

// 16x32 job: one A-frag stream, two B-tiles. COH: A via coherent path.
template<bool COH>
static __device__ __forceinline__ void gemm16x2(const ushort* __restrict__ A,
    const ushort* __restrict__ Bt, int m0, int n0, f32x4& acc0, f32x4& acc1)
{
  const int l  = threadIdx.x & 63;
  const int fr = l & 15, kg = (l >> 4) << 3;
  const ushort* pa  = A  + (size_t)(m0 + fr) * DH + kg;
  const ushort* pb0 = Bt + (size_t)(n0 + fr) * DH + kg;
  const ushort* pb1 = pb0 + 16 * DH;
#pragma unroll 4
  for (int kt = 0; kt < DH; kt += 32) {
    const bf16x8 a  = COH ? ldfrag_c(pa + kt) : *(const bf16x8*)(pa + kt);
    const bf16x8 b0 = *(const bf16x8*)(pb0 + kt);
    const bf16x8 b1 = *(const bf16x8*)(pb1 + kt);
    acc0 = __builtin_amdgcn_mfma_f32_16x16x32_bf16(a, b0, acc0, 0, 0, 0);
    acc1 = __builtin_amdgcn_mfma_f32_16x16x32_bf16(a, b1, acc1, 0, 0, 0);
  }
}

__global__ __launch_bounds__(NTHR) void mega(PARAMS p)
{
  const int tid  = threadIdx.x;
  const int bid  = blockIdx.x;
  const int widx = tid >> 6;
  const int lane = tid & 63;
  const int fr   = lane & 15, rg = (lane >> 4) << 2;
  const float c1  = 0.57707801635558534f;   // 2*log2(e)/C
  const float Ac  = 7.2134752044448169f;    // C*log2(e)
  const float Bc  = 14.426950408889634f;    // 2C*log2(e)
  const float l2e = 1.4426950408889634f;

  // ---------- P1: rep = elu(x@fc_w + fc_b); coherent stores rep/repb/dr.y ----------
  {
    const int wv = widx * NBLK + bid;
    if (wv < 512) {                                   // 32 m-tiles x 16 n2-tiles
      const int m0 = (wv >> 4) << 4, n0 = (wv & 15) << 5;
      f32x4 acc[2] = {};
      gemm16x2<false>(p.xb, p.fcwt, m0, n0, acc[0], acc[1]);
#pragma unroll
      for (int f = 0; f < 2; ++f) {
        const int col = n0 + f * 16 + fr;
        const float bv = p.fcb[col];
#pragma unroll
        for (int r = 0; r < 4; ++r) {
          float v = acc[f][r] + bv;
          v = v > 0.0f ? v : (__builtin_amdgcn_exp2f(v * l2e) - 1.0f);
          const size_t idx = (size_t)(m0 + rg + r) * DH + col;
          cstf(p.rep + idx, v);
          csth(p.repb + idx, f2b(v));
          cstf(p.dr + idx * 2 + 1, v);
        }
      }
    }
  }
  gridbar(p.bar, 0);

  // ---------- P2: dr.x=(rep@w1+b1+bl)*c1 ; hsc=(rep@w2+b2)*c1 ; g1=rep@wf1 ----------
  {
    const int wv = widx * NBLK + bid;
    if (wv < 1536) {                                  // 3 GEMMs x 512 jobs
      const int z = wv >> 9, rem = wv & 511;
      const int m0 = (rem >> 4) << 4, n0 = (rem & 15) << 5;
      const ushort* Bt = (z == 0) ? p.w1t : (z == 1) ? p.w2t : p.wf1t;
      f32x4 acc[2] = {};
      gemm16x2<true>(p.repb, Bt, m0, n0, acc[0], acc[1]);
#pragma unroll
      for (int f = 0; f < 2; ++f) {
        const int col = n0 + f * 16 + fr;
#pragma unroll
        for (int r = 0; r < 4; ++r) {
          const size_t idx = (size_t)(m0 + rg + r) * DH + col;
          if (z == 0)      cstf(p.dr + idx * 2, (acc[f][r] + p.b1[col] + p.bl[col]) * c1);
          else if (z == 1) cstf(p.hsc + idx, (acc[f][r] + p.b2[col]) * c1);
          else             cstf(p.g1 + idx, acc[f][r]);
        }
      }
    }
  }
  gridbar(p.bar, 1);

  // ---------- P3: balanced masked tanh-clip softmax attention, rows {i1, 255-i1} ----------
  // w = 2^(Ac - Bc*rcp(E+1)), E_row2 = E_row1 * 2^(hb2-hb1) (shared exponent)
  {
    const int b = bid >> 7, i1 = bid & 127, i2 = 255 - i1;
    const int h = tid;
    const bool special = (i1 == 0);                   // pair contains row 255
    const float hb1 = cldf(p.hsc + ((size_t)b * L + i1) * DH + h);
    const float hb2 = cldf(p.hsc + ((size_t)b * L + i2) * DH + h);
    const float delta = __builtin_amdgcn_exp2f(hb2 - hb1);
    const float* drp = p.dr + ((size_t)b * L * DH + h) * 2;
    float sa1 = 0.0f, aa1 = 0.0f, sa2 = 0.0f, aa2 = 0.0f;
    const int jstart = special ? 0 : (i1 + 1);
    for (int j = jstart; j < L; ++j) {
      union { u64 q; float2 v; } u;
      u.q = cld8(drp + (size_t)j * (DH * 2));         // {d*c1, rep}
      const float E1 = __builtin_amdgcn_exp2f(u.v.x + hb1);
      if (j > i1) {                                   // block-uniform
        const float w = __builtin_amdgcn_exp2f(
            fmaf(-Bc, __builtin_amdgcn_rcpf(E1 + 1.0f), Ac));
        sa1 += w; aa1 = fmaf(w, u.v.y, aa1);
      }
      if (special) {                                  // row 255: uniform weights
        sa2 += 1.0f; aa2 += u.v.y;
      } else if (j > i2) {
        const float E2 = E1 * delta;
        const float w = __builtin_amdgcn_exp2f(
            fmaf(-Bc, __builtin_amdgcn_rcpf(E2 + 1.0f), Ac));
        sa2 += w; aa2 = fmaf(w, u.v.y, aa2);
      }
    }
    const float v1 = aa1 * __builtin_amdgcn_rcpf(sa1);
    const float v2 = aa2 * __builtin_amdgcn_rcpf(sa2);
    const size_t o1 = ((size_t)b * L + i1) * DH + h;
    const size_t o2 = ((size_t)b * L + i2) * DH + h;
    cstf(p.attn + o1, v1); csth(p.attnb + o1, f2b(v1));
    cstf(p.attn + o2, v2); csth(p.attnb + o2, f2b(v2));
  }
  gridbar(p.bar, 2);

  // ---------- P4: g2 = attn@wf2 ; gate = sigmoid(g1+g2+bf) ; out = mix ----------
  {
    const int wv = widx * NBLK + bid;
    if (wv < 512) {
      const int m0 = (wv >> 4) << 4, n0 = (wv & 15) << 5;
      f32x4 acc[2] = {};
      gemm16x2<true>(p.attnb, p.wf2t, m0, n0, acc[0], acc[1]);
#pragma unroll
      for (int f = 0; f < 2; ++f) {
        const int col = n0 + f * 16 + fr;
        const float bv = p.bf[col];
#pragma unroll
        for (int r = 0; r < 4; ++r) {
          const size_t idx = (size_t)(m0 + rg + r) * DH + col;
          const float s = cldf(p.g1 + idx) + acc[f][r] + bv;
          const float gate = __builtin_amdgcn_rcpf(
              1.0f + __builtin_amdgcn_exp2f(-s * l2e));
          p.out[idx] = gate * cldf(p.rep + idx) + (1.0f - gate) * cldf(p.attn + idx);
        }
      }
    }
  }
}

extern "C" void kernel_launch(void* const* d_in, const int* in_sizes, int n_in,
                              void* d_out, int out_size, void* d_ws, size_t ws_size,
                              hipStream_t stream)
{
  const float* x   = (const float*)d_in[0];
  const float* fcw = (const float*)d_in[1];
  const float* w1  = (const float*)d_in[3];
  const float* w2  = (const float*)d_in[5];
  const float* wf1 = (const float*)d_in[8];
  const float* wf2 = (const float*)d_in[9];

  PARAMS p;
  p.fcb = (const float*)d_in[2];
  p.b1  = (const float*)d_in[4];
  p.b2  = (const float*)d_in[6];
  p.bl  = (const float*)d_in[7];
  p.bf  = (const float*)d_in[10];
  p.out = (float*)d_out;

  float* ws = (float*)d_ws;
  p.rep  = ws;                 // MAT
  p.g1   = ws + 1 * MAT;
  p.attn = ws + 2 * MAT;
  p.hsc  = ws + 3 * MAT;
  p.dr   = ws + 4 * MAT;       // 2*MAT: float2 {d*c1, rep}
  ushort* ub = (ushort*)(ws + 6 * MAT);
  ushort* xb   = ub + 0 * MAT;
  p.repb       = ub + 1 * MAT;
  p.attnb      = ub + 2 * MAT;
  ushort* fcwt = ub + 3 * MAT;
  ushort* w1t  = ub + 4 * MAT;
  ushort* w2t  = ub + 5 * MAT;
  ushort* wf1t = ub + 6 * MAT;
  ushort* wf2t = ub + 7 * MAT;
  p.xb = xb; p.fcwt = fcwt; p.w1t = w1t; p.w2t = w2t; p.wf1t = wf1t; p.wf2t = wf2t;
  p.bar = (int*)(ws + 10 * MAT);

  hipMemsetAsync(p.bar, 0, 3 * 512 * sizeof(int), stream);
  k_conv<<<dim3(16, 16, 6), dim3(256), 0, stream>>>(x, fcw, w1, w2, wf1, wf2,
                                                    xb, fcwt, w1t, w2t, wf1t, wf2t);
  void* args[] = { &p };
  hipLaunchCooperativeKernel((void*)mega, dim3(NBLK), dim3(NTHR), args, 0, stream);
}

// Round 7
// 112.217 us; speedup vs baseline: 2.1397x; 1.0650x over previous
//
#include <hip/hip_runtime.h>
#include <hip/hip_bf16.h>

#define L 256
#define DH 512
#define NBLK 256
#define NTHR 512
#define MAT 262144
#define AGT __HIP_MEMORY_SCOPE_AGENT

typedef __attribute__((ext_vector_type(8))) short bf16x8;
typedef __attribute__((ext_vector_type(4))) float f32x4;
typedef unsigned long long u64;

static __device__ __forceinline__ ushort f2b(float v) {
  __hip_bfloat16 h = __float2bfloat16(v);
  return *(ushort*)&h;
}
// Write-through agent-scope stores: data lands at the coherent Infinity Cache.
// Consumers (post-barrier, first touch per XCD) use PLAIN cached loads.
static __device__ __forceinline__ void cstf(float* p, float v) {
  __hip_atomic_store(p, v, __ATOMIC_RELAXED, AGT);
}
static __device__ __forceinline__ void csth(ushort* p, ushort v) {
  __hip_atomic_store(p, v, __ATOMIC_RELAXED, AGT);
}
static __device__ __forceinline__ void cst8(void* p, u64 v) {
  __hip_atomic_store((u64*)p, v, __ATOMIC_RELAXED, AGT);
}

struct PARAMS {
  const float *x, *fcw, *w1, *w2, *wf1, *wf2;
  const float *fcb, *b1, *b2, *bl, *bf;
  float *out, *rep, *g1, *attn, *hsc, *dr;
  ushort *xb, *repb, *attnb, *fcwt, *w1t, *w2t, *wf1t, *wf2t;
  int *bar;   // 4 phases x 512 ints, zeroed each call
};

// relaxed-only hierarchical grid barrier; signal fences = compiler-order only
static __device__ __forceinline__ void gridbar(int* bar, int ph) {
  __syncthreads();                       // drains vmcnt -> sc1 stores at IF
  if (threadIdx.x == 0) {
    __atomic_signal_fence(__ATOMIC_SEQ_CST);
    int* base = bar + ph * 512;
    int* cnt  = base + (blockIdx.x & 7) * 32;
    if (__hip_atomic_fetch_add(cnt, 1, __ATOMIC_RELAXED, AGT) == 31) {
      if (__hip_atomic_fetch_add(base + 256, 1, __ATOMIC_RELAXED, AGT) == 7)
        __hip_atomic_store(base + 288, 1, __ATOMIC_RELAXED, AGT);
    }
    while (!__hip_atomic_load(base + 288, __ATOMIC_RELAXED, AGT))
      __builtin_amdgcn_s_sleep(1);
    __atomic_signal_fence(__ATOMIC_SEQ_CST);
  }
  __syncthreads();
}

// 16x16 tile, K=512, one wave; plain cached loads (both operands [row][K] bf16)
static __device__ __forceinline__ void gemm16(const ushort* __restrict__ A,
    const ushort* __restrict__ Bt, int m0, int n0, f32x4& acc)
{
  const int l  = threadIdx.x & 63;
  const int fr = l & 15, kg = (l >> 4) << 3;
  const ushort* pa = A  + (size_t)(m0 + fr) * DH + kg;
  const ushort* pb = Bt + (size_t)(n0 + fr) * DH + kg;
#pragma unroll 8
  for (int kt = 0; kt < DH; kt += 32)
    acc = __builtin_amdgcn_mfma_f32_16x16x32_bf16(*(const bf16x8*)(pa + kt),
                                                  *(const bf16x8*)(pb + kt), acc, 0, 0, 0);
}

// 16x32 job: one A-frag stream, two B-tiles
static __device__ __forceinline__ void gemm16x2(const ushort* __restrict__ A,
    const ushort* __restrict__ Bt, int m0, int n0, f32x4& acc0, f32x4& acc1)
{
  const int l  = threadIdx.x & 63;
  const int fr = l & 15, kg = (l >> 4) << 3;
  const ushort* pa  = A  + (size_t)(m0 + fr) * DH + kg;
  const ushort* pb0 = Bt + (size_t)(n0 + fr) * DH + kg;
  const ushort* pb1 = pb0 + 16 * DH;
#pragma unroll 4
  for (int kt = 0; kt < DH; kt += 32) {
    const bf16x8 a  = *(const bf16x8*)(pa + kt);
    acc0 = __builtin_amdgcn_mfma_f32_16x16x32_bf16(a, *(const bf16x8*)(pb0 + kt), acc0, 0, 0, 0);
    acc1 = __builtin_amdgcn_mfma_f32_16x16x32_bf16(a, *(const bf16x8*)(pb1 + kt), acc1, 0, 0, 0);
  }
}

__global__ __launch_bounds__(NTHR) void mega(PARAMS p)
{
  const int tid  = threadIdx.x;
  const int bid  = blockIdx.x;
  const int widx = tid >> 6;
  const int lane = tid & 63;
  const int fr   = lane & 15, rg = (lane >> 4) << 2;
  const float c1  = 0.57707801635558534f;   // 2*log2(e)/C
  const float Ac  = 7.2134752044448169f;    // C*log2(e)
  const float Bc  = 14.426950408889634f;    // 2C*log2(e)
  const float l2e = 1.4426950408889634f;

  // ---------- P0: cast x -> xb ; transpose+cast 5 weights to [N][K] bf16 (sc1 stores) ----------
  {
    const int gid = bid * NTHR + tid;
    if (gid < 65536) {
      const float4 v = ((const float4*)p.x)[gid];
      union { ushort4 s; u64 q; } o;
      o.s.x = f2b(v.x); o.s.y = f2b(v.y); o.s.z = f2b(v.z); o.s.w = f2b(v.w);
      cst8((ushort4*)p.xb + gid, o.q);
    }
    __shared__ float tr[32][33];
    const int tx = tid & 31, ty = tid >> 5;             // ty in [0,16)
    const int r0 = (bid >> 4) << 5, c0 = (bid & 15) << 5;
    const float* srcs[5] = {p.fcw, p.w1, p.w2, p.wf1, p.wf2};
    ushort*      dsts[5] = {p.fcwt, p.w1t, p.w2t, p.wf1t, p.wf2t};
#pragma unroll
    for (int s = 0; s < 5; ++s) {
      __syncthreads();
      tr[ty][tx]      = srcs[s][(size_t)(r0 + ty) * DH + c0 + tx];
      tr[ty + 16][tx] = srcs[s][(size_t)(r0 + ty + 16) * DH + c0 + tx];
      __syncthreads();
      csth(&dsts[s][(size_t)(c0 + ty) * DH + r0 + tx],      f2b(tr[tx][ty]));
      csth(&dsts[s][(size_t)(c0 + ty + 16) * DH + r0 + tx], f2b(tr[tx][ty + 16]));
    }
  }
  gridbar(p.bar, 0);

  // ---------- P1: rep = elu(x@fc_w + fc_b); sc1 stores rep/repb/dr.y ----------
  {
    const int wv = widx * NBLK + bid;
    if (wv < 1024) {                                  // 1024 jobs of 16x16
      const int m0 = (wv >> 5) << 4, n0 = (wv & 31) << 4;
      f32x4 acc = {};
      gemm16(p.xb, p.fcwt, m0, n0, acc);
      const int col = n0 + fr;
      const float bv = p.fcb[col];
#pragma unroll
      for (int r = 0; r < 4; ++r) {
        float v = acc[r] + bv;
        v = v > 0.0f ? v : (__builtin_amdgcn_exp2f(v * l2e) - 1.0f);
        const size_t idx = (size_t)(m0 + rg + r) * DH + col;
        cstf(p.rep + idx, v);
        csth(p.repb + idx, f2b(v));
        cstf(p.dr + idx * 2 + 1, v);
      }
    }
  }
  gridbar(p.bar, 1);

  // ---------- P2: dr.x = 2^((rep@w1+b1+bl)*c1) ; hsc = 2^((rep@w2+b2)*c1) ; g1 = rep@wf1 ----------
  {
    const int wv = widx * NBLK + bid;
    if (wv < 1536) {                                  // 3 GEMMs x 512 16x32 jobs
      const int z = wv >> 9, rem = wv & 511;
      const int m0 = (rem >> 4) << 4, n0 = (rem & 15) << 5;
      const ushort* Bt = (z == 0) ? p.w1t : (z == 1) ? p.w2t : p.wf1t;
      f32x4 acc[2] = {};
      gemm16x2(p.repb, Bt, m0, n0, acc[0], acc[1]);
#pragma unroll
      for (int f = 0; f < 2; ++f) {
        const int col = n0 + f * 16 + fr;
#pragma unroll
        for (int r = 0; r < 4; ++r) {
          const size_t idx = (size_t)(m0 + rg + r) * DH + col;
          if (z == 0)
            cstf(p.dr + idx * 2,
                 __builtin_amdgcn_exp2f((acc[f][r] + p.b1[col] + p.bl[col]) * c1));
          else if (z == 1)
            cstf(p.hsc + idx,
                 __builtin_amdgcn_exp2f((acc[f][r] + p.b2[col]) * c1));
          else
            cstf(p.g1 + idx, acc[f][r]);
        }
      }
    }
  }
  gridbar(p.bar, 2);

  // ---------- P3: masked tanh-clip softmax attention, rows {i1, 255-i1} per block ----------
  // E = E_d * E_h ; w = 2^(Ac - Bc*rcp(E+1)) ; row 255 fully masked -> uniform weights
  {
    const int b = bid >> 7, i1 = bid & 127, i2 = 255 - i1;
    const int h = tid;
    const bool special = (i1 == 0);                   // pair contains row 255
    const float Eh1 = p.hsc[((size_t)b * L + i1) * DH + h];
    const float Eh2 = p.hsc[((size_t)b * L + i2) * DH + h];
    const float2* drp = (const float2*)p.dr + (size_t)b * L * DH + h;
    float sa1 = 0.0f, aa1 = 0.0f, sa2 = 0.0f, aa2 = 0.0f;
    const int jstart = special ? 0 : (i1 + 1);
    for (int j = jstart; j < L; ++j) {
      const float2 v = drp[(size_t)j * DH];           // {E_d, rep}
      if (j > i1) {                                   // block-uniform branch
        const float E = v.x * Eh1;
        const float w = __builtin_amdgcn_exp2f(
            fmaf(-Bc, __builtin_amdgcn_rcpf(E + 1.0f), Ac));
        sa1 += w; aa1 = fmaf(w, v.y, aa1);
      }
      if (special) {                                  // row 255: uniform weights
        sa2 += 1.0f; aa2 += v.y;
      } else if (j > i2) {
        const float E = v.x * Eh2;
        const float w = __builtin_amdgcn_exp2f(
            fmaf(-Bc, __builtin_amdgcn_rcpf(E + 1.0f), Ac));
        sa2 += w; aa2 = fmaf(w, v.y, aa2);
      }
    }
    const float v1 = aa1 * __builtin_amdgcn_rcpf(sa1);
    const float v2 = aa2 * __builtin_amdgcn_rcpf(sa2);
    const size_t o1 = ((size_t)b * L + i1) * DH + h;
    const size_t o2 = ((size_t)b * L + i2) * DH + h;
    cstf(p.attn + o1, v1); csth(p.attnb + o1, f2b(v1));
    cstf(p.attn + o2, v2); csth(p.attnb + o2, f2b(v2));
  }
  gridbar(p.bar, 3);

  // ---------- P4: g2 = attn@wf2 ; gate = sigmoid(g1+g2+bf) ; out = mix (plain) ----------
  {
    const int wv = widx * NBLK + bid;
    if (wv < 1024) {
      const int m0 = (wv >> 5) << 4, n0 = (wv & 31) << 4;
      f32x4 acc = {};
      gemm16(p.attnb, p.wf2t, m0, n0, acc);
      const int col = n0 + fr;
      const float bv = p.bf[col];
#pragma unroll
      for (int r = 0; r < 4; ++r) {
        const size_t idx = (size_t)(m0 + rg + r) * DH + col;
        const float s = p.g1[idx] + acc[r] + bv;
        const float gate = __builtin_amdgcn_rcpf(
            1.0f + __builtin_amdgcn_exp2f(-s * l2e));
        p.out[idx] = gate * p.rep[idx] + (1.0f - gate) * p.attn[idx];
      }
    }
  }
}

extern "C" void kernel_launch(void* const* d_in, const int* in_sizes, int n_in,
                              void* d_out, int out_size, void* d_ws, size_t ws_size,
                              hipStream_t stream)
{
  PARAMS p;
  p.x   = (const float*)d_in[0];
  p.fcw = (const float*)d_in[1];
  p.fcb = (const float*)d_in[2];
  p.w1  = (const float*)d_in[3];
  p.b1  = (const float*)d_in[4];
  p.w2  = (const float*)d_in[5];
  p.b2  = (const float*)d_in[6];
  p.bl  = (const float*)d_in[7];
  p.wf1 = (const float*)d_in[8];
  p.wf2 = (const float*)d_in[9];
  p.bf  = (const float*)d_in[10];
  p.out = (float*)d_out;

  float* ws = (float*)d_ws;
  p.rep  = ws;                 // MAT
  p.g1   = ws + 1 * MAT;
  p.attn = ws + 2 * MAT;
  p.hsc  = ws + 3 * MAT;       // E_h = 2^(head'*c1)
  p.dr   = ws + 4 * MAT;       // 2*MAT: float2 {E_d, rep}
  ushort* ub = (ushort*)(ws + 6 * MAT);
  p.xb    = ub + 0 * MAT;
  p.repb  = ub + 1 * MAT;
  p.attnb = ub + 2 * MAT;
  p.fcwt  = ub + 3 * MAT;
  p.w1t   = ub + 4 * MAT;
  p.w2t   = ub + 5 * MAT;
  p.wf1t  = ub + 6 * MAT;
  p.wf2t  = ub + 7 * MAT;
  p.bar   = (int*)(ws + 10 * MAT);

  hipMemsetAsync(p.bar, 0, 4 * 512 * sizeof(int), stream);
  void* args[] = { &p };
  hipLaunchCooperativeKernel((void*)mega, dim3(NBLK), dim3(NTHR), args, 0, stream);
}

// Round 8
// 111.896 us; speedup vs baseline: 2.1458x; 1.0029x over previous
//
#include <hip/hip_runtime.h>
#include <hip/hip_bf16.h>

#define L 256
#define DH 512
#define NBLK 256
#define NTHR 512
#define MAT 262144
#define NPH 4
#define AGT __HIP_MEMORY_SCOPE_AGENT

typedef __attribute__((ext_vector_type(8))) short bf16x8;
typedef __attribute__((ext_vector_type(4))) float f32x4;
typedef unsigned long long u64;

static __device__ __forceinline__ ushort f2b(float v) {
  __hip_bfloat16 h = __float2bfloat16(v);
  return *(ushort*)&h;
}
// Write-through agent-scope stores: data lands at the coherent Infinity Cache.
// Consumers (post-barrier, first touch per XCD) use PLAIN cached loads.
static __device__ __forceinline__ void cstf(float* p, float v) {
  __hip_atomic_store(p, v, __ATOMIC_RELAXED, AGT);
}
static __device__ __forceinline__ void csth(ushort* p, ushort v) {
  __hip_atomic_store(p, v, __ATOMIC_RELAXED, AGT);
}
static __device__ __forceinline__ void cst8(void* p, u64 v) {
  __hip_atomic_store((u64*)p, v, __ATOMIC_RELAXED, AGT);
}

struct PARAMS {
  const float *x, *fcw, *w1, *w2, *wf1, *wf2;
  const float *fcb, *b1, *b2, *bl, *bf;
  float *out, *rep, *g1, *attn, *hsc, *dr;
  ushort *xb, *repb, *attnb, *fcwt, *w1t, *w2t, *wf1t, *wf2t;
  int *bar;   // NPH*4096 flag ints (one 64B line per block) + NPH*16 release ints
};

// zero-RMW grid barrier: parallel flag stores; block 0 polls all flags with
// 255 threads concurrently, then publishes a release word. No atomics chains,
// no cache maintenance (all flag traffic is relaxed agent scope -> IF).
static __device__ __forceinline__ void gridbar(int* bar, int ph) {
  __syncthreads();                       // all waves done; stores drained (vmcnt)
  int* flags = bar + ph * 4096;          // flag of block b at flags[b*16]
  int* rel   = bar + NPH * 4096 + ph * 16;
  const int tid = threadIdx.x;
  if (blockIdx.x == 0) {
    if (tid > 0 && tid < NBLK) {
      while (!__hip_atomic_load(flags + tid * 16, __ATOMIC_RELAXED, AGT))
        __builtin_amdgcn_s_sleep(1);
    }
    __syncthreads();
    if (tid == 0)
      __hip_atomic_store(rel, 1, __ATOMIC_RELAXED, AGT);
  } else if (tid == 0) {
    __hip_atomic_store(flags + blockIdx.x * 16, 1, __ATOMIC_RELAXED, AGT);
    while (!__hip_atomic_load(rel, __ATOMIC_RELAXED, AGT))
      __builtin_amdgcn_s_sleep(1);
  }
  __syncthreads();
}

// 16x16 tile, K=512, one wave; plain cached loads (both operands [row][K] bf16)
static __device__ __forceinline__ void gemm16(const ushort* __restrict__ A,
    const ushort* __restrict__ Bt, int m0, int n0, f32x4& acc)
{
  const int l  = threadIdx.x & 63;
  const int fr = l & 15, kg = (l >> 4) << 3;
  const ushort* pa = A  + (size_t)(m0 + fr) * DH + kg;
  const ushort* pb = Bt + (size_t)(n0 + fr) * DH + kg;
#pragma unroll 8
  for (int kt = 0; kt < DH; kt += 32)
    acc = __builtin_amdgcn_mfma_f32_16x16x32_bf16(*(const bf16x8*)(pa + kt),
                                                  *(const bf16x8*)(pb + kt), acc, 0, 0, 0);
}

// 16x32 job: one A-frag stream, two B-tiles
static __device__ __forceinline__ void gemm16x2(const ushort* __restrict__ A,
    const ushort* __restrict__ Bt, int m0, int n0, f32x4& acc0, f32x4& acc1)
{
  const int l  = threadIdx.x & 63;
  const int fr = l & 15, kg = (l >> 4) << 3;
  const ushort* pa  = A  + (size_t)(m0 + fr) * DH + kg;
  const ushort* pb0 = Bt + (size_t)(n0 + fr) * DH + kg;
  const ushort* pb1 = pb0 + 16 * DH;
#pragma unroll 4
  for (int kt = 0; kt < DH; kt += 32) {
    const bf16x8 a  = *(const bf16x8*)(pa + kt);
    acc0 = __builtin_amdgcn_mfma_f32_16x16x32_bf16(a, *(const bf16x8*)(pb0 + kt), acc0, 0, 0, 0);
    acc1 = __builtin_amdgcn_mfma_f32_16x16x32_bf16(a, *(const bf16x8*)(pb1 + kt), acc1, 0, 0, 0);
  }
}

__global__ __launch_bounds__(NTHR) void mega(PARAMS p)
{
  const int tid  = threadIdx.x;
  const int bid  = blockIdx.x;
  const int widx = tid >> 6;
  const int lane = tid & 63;
  const int fr   = lane & 15, rg = (lane >> 4) << 2;
  const float c1  = 0.57707801635558534f;   // 2*log2(e)/C
  const float Ac  = 7.2134752044448169f;    // C*log2(e)
  const float Bc  = 14.426950408889634f;    // 2C*log2(e)
  const float l2e = 1.4426950408889634f;

  // ---------- P0: cast x -> xb ; transpose+cast 5 weights to [N][K] bf16 (sc1 stores) ----------
  {
    const int gid = bid * NTHR + tid;
    if (gid < 65536) {
      const float4 v = ((const float4*)p.x)[gid];
      union { ushort4 s; u64 q; } o;
      o.s.x = f2b(v.x); o.s.y = f2b(v.y); o.s.z = f2b(v.z); o.s.w = f2b(v.w);
      cst8((ushort4*)p.xb + gid, o.q);
    }
    __shared__ float tr[32][33];
    const int tx = tid & 31, ty = tid >> 5;             // ty in [0,16)
    const int r0 = (bid >> 4) << 5, c0 = (bid & 15) << 5;
    const float* srcs[5] = {p.fcw, p.w1, p.w2, p.wf1, p.wf2};
    ushort*      dsts[5] = {p.fcwt, p.w1t, p.w2t, p.wf1t, p.wf2t};
#pragma unroll
    for (int s = 0; s < 5; ++s) {
      __syncthreads();
      tr[ty][tx]      = srcs[s][(size_t)(r0 + ty) * DH + c0 + tx];
      tr[ty + 16][tx] = srcs[s][(size_t)(r0 + ty + 16) * DH + c0 + tx];
      __syncthreads();
      csth(&dsts[s][(size_t)(c0 + ty) * DH + r0 + tx],      f2b(tr[tx][ty]));
      csth(&dsts[s][(size_t)(c0 + ty + 16) * DH + r0 + tx], f2b(tr[tx][ty + 16]));
    }
  }
  gridbar(p.bar, 0);

  // ---------- P1: rep = elu(x@fc_w + fc_b); sc1 stores rep/repb/dr.y ----------
  {
    const int wv = widx * NBLK + bid;
    if (wv < 1024) {                                  // 1024 jobs of 16x16
      const int m0 = (wv >> 5) << 4, n0 = (wv & 31) << 4;
      f32x4 acc = {};
      gemm16(p.xb, p.fcwt, m0, n0, acc);
      const int col = n0 + fr;
      const float bv = p.fcb[col];
#pragma unroll
      for (int r = 0; r < 4; ++r) {
        float v = acc[r] + bv;
        v = v > 0.0f ? v : (__builtin_amdgcn_exp2f(v * l2e) - 1.0f);
        const size_t idx = (size_t)(m0 + rg + r) * DH + col;
        cstf(p.rep + idx, v);
        csth(p.repb + idx, f2b(v));
        cstf(p.dr + idx * 2 + 1, v);
      }
    }
  }
  gridbar(p.bar, 1);

  // ---------- P2: dr.x = 2^((rep@w1+b1+bl)*c1) ; hsc = 2^((rep@w2+b2)*c1) ; g1 = rep@wf1 ----------
  {
    const int wv = widx * NBLK + bid;
    if (wv < 1536) {                                  // 3 GEMMs x 512 16x32 jobs
      const int z = wv >> 9, rem = wv & 511;
      const int m0 = (rem >> 4) << 4, n0 = (rem & 15) << 5;
      const ushort* Bt = (z == 0) ? p.w1t : (z == 1) ? p.w2t : p.wf1t;
      f32x4 acc[2] = {};
      gemm16x2(p.repb, Bt, m0, n0, acc[0], acc[1]);
#pragma unroll
      for (int f = 0; f < 2; ++f) {
        const int col = n0 + f * 16 + fr;
#pragma unroll
        for (int r = 0; r < 4; ++r) {
          const size_t idx = (size_t)(m0 + rg + r) * DH + col;
          if (z == 0)
            cstf(p.dr + idx * 2,
                 __builtin_amdgcn_exp2f((acc[f][r] + p.b1[col] + p.bl[col]) * c1));
          else if (z == 1)
            cstf(p.hsc + idx,
                 __builtin_amdgcn_exp2f((acc[f][r] + p.b2[col]) * c1));
          else
            cstf(p.g1 + idx, acc[f][r]);
        }
      }
    }
  }
  gridbar(p.bar, 2);

  // ---------- P3: masked tanh-clip softmax attention, rows {i1, 255-i1} per block ----------
  // E = E_d * E_h ; w = 2^(Ac - Bc*rcp(E+1)) ; row 255 fully masked -> uniform weights
  {
    const int b = bid >> 7, i1 = bid & 127, i2 = 255 - i1;
    const int h = tid;
    const bool special = (i1 == 0);                   // pair contains row 255
    const float Eh1 = p.hsc[((size_t)b * L + i1) * DH + h];
    const float Eh2 = p.hsc[((size_t)b * L + i2) * DH + h];
    const float2* drp = (const float2*)p.dr + (size_t)b * L * DH + h;
    float sa1 = 0.0f, aa1 = 0.0f, sa2 = 0.0f, aa2 = 0.0f;
    const int jstart = special ? 0 : (i1 + 1);
    for (int j = jstart; j < L; ++j) {
      const float2 v = drp[(size_t)j * DH];           // {E_d, rep}
      if (j > i1) {                                   // block-uniform branch
        const float E = v.x * Eh1;
        const float w = __builtin_amdgcn_exp2f(
            fmaf(-Bc, __builtin_amdgcn_rcpf(E + 1.0f), Ac));
        sa1 += w; aa1 = fmaf(w, v.y, aa1);
      }
      if (special) {                                  // row 255: uniform weights
        sa2 += 1.0f; aa2 += v.y;
      } else if (j > i2) {
        const float E = v.x * Eh2;
        const float w = __builtin_amdgcn_exp2f(
            fmaf(-Bc, __builtin_amdgcn_rcpf(E + 1.0f), Ac));
        sa2 += w; aa2 = fmaf(w, v.y, aa2);
      }
    }
    const float v1 = aa1 * __builtin_amdgcn_rcpf(sa1);
    const float v2 = aa2 * __builtin_amdgcn_rcpf(sa2);
    const size_t o1 = ((size_t)b * L + i1) * DH + h;
    const size_t o2 = ((size_t)b * L + i2) * DH + h;
    cstf(p.attn + o1, v1); csth(p.attnb + o1, f2b(v1));
    cstf(p.attn + o2, v2); csth(p.attnb + o2, f2b(v2));
  }
  gridbar(p.bar, 3);

  // ---------- P4: g2 = attn@wf2 ; gate = sigmoid(g1+g2+bf) ; out = mix (plain) ----------
  {
    const int wv = widx * NBLK + bid;
    if (wv < 1024) {
      const int m0 = (wv >> 5) << 4, n0 = (wv & 31) << 4;
      f32x4 acc = {};
      gemm16(p.attnb, p.wf2t, m0, n0, acc);
      const int col = n0 + fr;
      const float bv = p.bf[col];
#pragma unroll
      for (int r = 0; r < 4; ++r) {
        const size_t idx = (size_t)(m0 + rg + r) * DH + col;
        const float s = p.g1[idx] + acc[r] + bv;
        const float gate = __builtin_amdgcn_rcpf(
            1.0f + __builtin_amdgcn_exp2f(-s * l2e));
        p.out[idx] = gate * p.rep[idx] + (1.0f - gate) * p.attn[idx];
      }
    }
  }
}

extern "C" void kernel_launch(void* const* d_in, const int* in_sizes, int n_in,
                              void* d_out, int out_size, void* d_ws, size_t ws_size,
                              hipStream_t stream)
{
  PARAMS p;
  p.x   = (const float*)d_in[0];
  p.fcw = (const float*)d_in[1];
  p.fcb = (const float*)d_in[2];
  p.w1  = (const float*)d_in[3];
  p.b1  = (const float*)d_in[4];
  p.w2  = (const float*)d_in[5];
  p.b2  = (const float*)d_in[6];
  p.bl  = (const float*)d_in[7];
  p.wf1 = (const float*)d_in[8];
  p.wf2 = (const float*)d_in[9];
  p.bf  = (const float*)d_in[10];
  p.out = (float*)d_out;

  float* ws = (float*)d_ws;
  p.rep  = ws;                 // MAT
  p.g1   = ws + 1 * MAT;
  p.attn = ws + 2 * MAT;
  p.hsc  = ws + 3 * MAT;       // E_h = 2^(head'*c1)
  p.dr   = ws + 4 * MAT;       // 2*MAT: float2 {E_d, rep}
  ushort* ub = (ushort*)(ws + 6 * MAT);
  p.xb    = ub + 0 * MAT;
  p.repb  = ub + 1 * MAT;
  p.attnb = ub + 2 * MAT;
  p.fcwt  = ub + 3 * MAT;
  p.w1t   = ub + 4 * MAT;
  p.w2t   = ub + 5 * MAT;
  p.wf1t  = ub + 6 * MAT;
  p.wf2t  = ub + 7 * MAT;
  p.bar   = (int*)(ws + 10 * MAT);

  hipMemsetAsync(p.bar, 0, (NPH * 4096 + NPH * 16) * sizeof(int), stream);
  void* args[] = { &p };
  hipLaunchCooperativeKernel((void*)mega, dim3(NBLK), dim3(NTHR), args, 0, stream);
}